// Round 1
// baseline (797.612 us; speedup 1.0000x reference)
//
#include <hip/hip_runtime.h>
#include <hip/hip_bf16.h>

#define B_    32
#define N_    6
#define D_    41
#define C_    64
#define FH_   4
#define FW_   6
#define INCH  768
#define HW    24
#define O_    105
#define PBN   984
#define PPB   5904
#define NPTS  188928
#define FINAL_ELEMS 81920000

// ws: feat f32[192*1536] | depth f32[NPTS] | cnt i32[128] | entries uint2[128*PPB]
// entries[b*4+q][slot] = { rel(14b) | nhw(8b)<<14 , depth bits }

// ---------------------------------------------------------------------------
// K1: fused conv + softmax. One block per image. x[bn] staged to LDS in two
// 36KB halves; each thread computes 3 output rows x 4 hw cols with fmaf.
// Epilogue: softmax over D in-block; depth->ws, logits->out, feat->ws.
// Also zeroes the bucket counters (block 0) for K2.
// ---------------------------------------------------------------------------
__global__ __launch_bounds__(256) void k_conv_fused(
    const float* __restrict__ x, const float* __restrict__ w,
    const float* __restrict__ bias,
    float* __restrict__ feat_ws, float* __restrict__ depth_ws,
    float* __restrict__ dlogit, int* __restrict__ cnt)
{
    __shared__ float xs[9216];      // half of x[bn]: 384 c x 24 hw (36 KB)
    __shared__ float ys[O_ * HW];   // full y image (10 KB)
    __shared__ float smax[HW], srs[HW];

    const int bn = blockIdx.x;
    const int t  = threadIdx.x;
    const int og = t / 6;           // 35 groups x 3 rows = 105
    const int q6 = t % 6;           // hw quad

    if (bn == 0 && t < 128) cnt[t] = 0;   // stream-ordered ahead of k_geom

    float a[3][4] = {{0.f,0.f,0.f,0.f},{0.f,0.f,0.f,0.f},{0.f,0.f,0.f,0.f}};
    const int o0 = og * 3;
    const float4* wr0 = (const float4*)(w + (size_t)(o0 + 0) * INCH);
    const float4* wr1 = (const float4*)(w + (size_t)(o0 + 1) * INCH);
    const float4* wr2 = (const float4*)(w + (size_t)(o0 + 2) * INCH);
    float4* xs4 = (float4*)xs;

    for (int half = 0; half < 2; ++half) {
        if (half) __syncthreads();                 // drain half-0 readers
        const float4* xg = (const float4*)(x + (size_t)bn * (INCH * HW)) + half * 2304;
        for (int i = t; i < 2304; i += 256) xs4[i] = xg[i];
        __syncthreads();

        if (t < 210) {
            const int wb = half * 96;              // float4 index into w row
            for (int c4 = 0; c4 < 96; ++c4) {
                float4 w0 = wr0[wb + c4];
                float4 w1 = wr1[wb + c4];
                float4 w2 = wr2[wb + c4];
                int cb = c4 * 4;
                float4 x0 = xs4[(cb + 0) * 6 + q6];
                float4 x1 = xs4[(cb + 1) * 6 + q6];
                float4 x2 = xs4[(cb + 2) * 6 + q6];
                float4 x3 = xs4[(cb + 3) * 6 + q6];
                a[0][0]=fmaf(w0.x,x0.x,a[0][0]); a[0][1]=fmaf(w0.x,x0.y,a[0][1]);
                a[0][2]=fmaf(w0.x,x0.z,a[0][2]); a[0][3]=fmaf(w0.x,x0.w,a[0][3]);
                a[1][0]=fmaf(w1.x,x0.x,a[1][0]); a[1][1]=fmaf(w1.x,x0.y,a[1][1]);
                a[1][2]=fmaf(w1.x,x0.z,a[1][2]); a[1][3]=fmaf(w1.x,x0.w,a[1][3]);
                a[2][0]=fmaf(w2.x,x0.x,a[2][0]); a[2][1]=fmaf(w2.x,x0.y,a[2][1]);
                a[2][2]=fmaf(w2.x,x0.z,a[2][2]); a[2][3]=fmaf(w2.x,x0.w,a[2][3]);
                a[0][0]=fmaf(w0.y,x1.x,a[0][0]); a[0][1]=fmaf(w0.y,x1.y,a[0][1]);
                a[0][2]=fmaf(w0.y,x1.z,a[0][2]); a[0][3]=fmaf(w0.y,x1.w,a[0][3]);
                a[1][0]=fmaf(w1.y,x1.x,a[1][0]); a[1][1]=fmaf(w1.y,x1.y,a[1][1]);
                a[1][2]=fmaf(w1.y,x1.z,a[1][2]); a[1][3]=fmaf(w1.y,x1.w,a[1][3]);
                a[2][0]=fmaf(w2.y,x1.x,a[2][0]); a[2][1]=fmaf(w2.y,x1.y,a[2][1]);
                a[2][2]=fmaf(w2.y,x1.z,a[2][2]); a[2][3]=fmaf(w2.y,x1.w,a[2][3]);
                a[0][0]=fmaf(w0.z,x2.x,a[0][0]); a[0][1]=fmaf(w0.z,x2.y,a[0][1]);
                a[0][2]=fmaf(w0.z,x2.z,a[0][2]); a[0][3]=fmaf(w0.z,x2.w,a[0][3]);
                a[1][0]=fmaf(w1.z,x2.x,a[1][0]); a[1][1]=fmaf(w1.z,x2.y,a[1][1]);
                a[1][2]=fmaf(w1.z,x2.z,a[1][2]); a[1][3]=fmaf(w1.z,x2.w,a[1][3]);
                a[2][0]=fmaf(w2.z,x2.x,a[2][0]); a[2][1]=fmaf(w2.z,x2.y,a[2][1]);
                a[2][2]=fmaf(w2.z,x2.z,a[2][2]); a[2][3]=fmaf(w2.z,x2.w,a[2][3]);
                a[0][0]=fmaf(w0.w,x3.x,a[0][0]); a[0][1]=fmaf(w0.w,x3.y,a[0][1]);
                a[0][2]=fmaf(w0.w,x3.z,a[0][2]); a[0][3]=fmaf(w0.w,x3.w,a[0][3]);
                a[1][0]=fmaf(w1.w,x3.x,a[1][0]); a[1][1]=fmaf(w1.w,x3.y,a[1][1]);
                a[1][2]=fmaf(w1.w,x3.z,a[1][2]); a[1][3]=fmaf(w1.w,x3.w,a[1][3]);
                a[2][0]=fmaf(w2.w,x3.x,a[2][0]); a[2][1]=fmaf(w2.w,x3.y,a[2][1]);
                a[2][2]=fmaf(w2.w,x3.z,a[2][2]); a[2][3]=fmaf(w2.w,x3.w,a[2][3]);
            }
        }
    }

    if (t < 210) {
#pragma unroll
        for (int r = 0; r < 3; r++) {
            float bo = bias[o0 + r];
#pragma unroll
            for (int j = 0; j < 4; j++)
                ys[(o0 + r) * HW + q6 * 4 + j] = a[r][j] + bo;
        }
    }
    __syncthreads();

    if (t < HW) {
        float mx = -1e30f;
        for (int d = 0; d < D_; d++) mx = fmaxf(mx, ys[d * HW + t]);
        float s = 0.f;
        for (int d = 0; d < D_; d++) s = __fadd_rn(s, expf(__fsub_rn(ys[d * HW + t], mx)));
        smax[t] = mx; srs[t] = s;
    }
    __syncthreads();

    for (int u = t; u < D_ * HW; u += 256) {
        float yv = ys[u];
        int hw = u % HW;
        depth_ws[bn * PBN + u] = __fdiv_rn(expf(__fsub_rn(yv, smax[hw])), srs[hw]);
        dlogit[(size_t)bn * PBN + u] = yv;
    }
    for (int u = t; u < C_ * HW; u += 256)
        feat_ws[(size_t)bn * (C_ * HW) + u] = ys[D_ * HW + u];
}

// ---------------------------------------------------------------------------
// K2: geometry + bucket compaction. Binning arithmetic is BIT-IDENTICAL to the
// validated frozen version; only the sink changed: instead of vox[p], kept
// points append {rel|nhw, depth} to the per-(b,quarter) entry list.
// ---------------------------------------------------------------------------
__global__ __launch_bounds__(256) void k_geom(
    const float* __restrict__ m1, const float* __restrict__ trans,
    const float* __restrict__ m2, const float* __restrict__ depth,
    int* __restrict__ cnt, uint2* __restrict__ entries)
{
    const float* rots = (fabsf(m1[0]) > 50.0f) ? m2 : m1;
    const float* intr = (fabsf(m1[0]) > 50.0f) ? m1 : m2;

    int p = blockIdx.x * 256 + threadIdx.x;   // 738*256 == 188928
    int b  = p / PPB;
    int pl = p % PPB;
    int n  = pl / PBN;
    int r  = pl % PBN;
    int d  = r / HW;
    int hw = r % HW;
    int h = hw / FW_, wp = hw % FW_;

    float dv = 4.0f + (float)d;
    float xi = (float)((double)wp * (199.0 / 5.0));
    float yi = (float)((double)h  * (149.0 / 3.0));
    float px = __fmul_rn(xi, dv), py = __fmul_rn(yi, dv), pz = dv;

    int bn = b * N_ + n;
    const float* K = intr + bn * 9;
    const float* R = rots + bn * 9;
    const float* T = trans + bn * 3;

    float a00 = K[0], a01 = K[1], a02 = K[2];
    float a11 = K[4], a12 = K[5];
    float a22 = K[8];

    float i00 = __fdiv_rn(1.0f, a00);
    float i11 = __fdiv_rn(1.0f, a11);
    float x0  = __fmul_rn(a01, i00);
    float i01 = __fmul_rn(-i11, x0);
    float i22 = __fdiv_rn(1.0f, a22);
    float y0  = __fmul_rn(a02, i00);
    y0 = __fadd_rn(y0, __fmul_rn(a12, i01));
    float y1  = __fmul_rn(a12, i11);
    float i02 = __fmul_rn(-i22, y0);
    float i12 = __fmul_rn(-i22, y1);
    float i10 = 0.f, i20 = 0.f, i21 = 0.f;

    float r00 = R[0], r01 = R[1], r02 = R[2];
    float r10 = R[3], r11 = R[4], r12 = R[5];
    float r20 = R[6], r21 = R[7], r22 = R[8];

#define MM(u0,u1,u2, v0,v1,v2) \
    __fmaf_rn(u2, v2, __fmaf_rn(u1, v1, __fmul_rn(u0, v0)))
    float c00 = MM(r00, r01, r02, i00, i10, i20);
    float c01 = MM(r00, r01, r02, i01, i11, i21);
    float c02 = MM(r00, r01, r02, i02, i12, i22);
    float c10 = MM(r10, r11, r12, i00, i10, i20);
    float c11 = MM(r10, r11, r12, i01, i11, i21);
    float c12 = MM(r10, r11, r12, i02, i12, i22);
    float c20 = MM(r20, r21, r22, i00, i10, i20);
    float c21 = MM(r20, r21, r22, i01, i11, i21);
    float c22 = MM(r20, r21, r22, i02, i12, i22);
#undef MM

#define DOT3(u0,v0,u1,v1,u2,v2) \
    __fadd_rn(__fadd_rn(__fmul_rn(u0,v0), __fmul_rn(u1,v1)), __fmul_rn(u2,v2))
    float gx = __fadd_rn(DOT3(c00,px, c01,py, c02,pz), T[0]);
    float gy = __fadd_rn(DOT3(c10,px, c11,py, c12,pz), T[1]);
    float gz = __fadd_rn(DOT3(c20,px, c21,py, c22,pz), T[2]);
#undef DOT3

    int ix = (int)__fmul_rn(__fadd_rn(gx, 50.0f), 2.0f);
    int iy = (int)__fmul_rn(__fadd_rn(gy, 50.0f), 2.0f);
    int iz = (int)__fdiv_rn(__fadd_rn(gz, 10.0f), 20.0f);
    bool kept = (ix >= 0) && (ix < 200) && (iy >= 0) && (iy < 200) && (iz == 0);

    if (kept) {
        int vl  = ix * 200 + iy;          // 0..39999
        int q   = vl / 10000;             // quarter 0..3
        int rel = vl - q * 10000;         // 0..9999  (14 bits)
        int nhw = n * HW + hw;            // 0..143   (8 bits)
        int slot = atomicAdd(&cnt[b * 4 + q], 1);   // slot < PPB guaranteed
        entries[(size_t)(b * 4 + q) * PPB + slot] =
            make_uint2((unsigned)rel | ((unsigned)nhw << 14),
                       __float_as_uint(depth[p]));
    }
}

// ---------------------------------------------------------------------------
// K3: splat -> f32 out. One block per (b,c,quarter); 40KB LDS plane; scans
// ONLY its quarter's compacted entry list (no divergence, no div/mod, feat
// pre-staged as a 144-float LDS table); LDS atomics; coalesced float4 stores.
// ---------------------------------------------------------------------------
__global__ __launch_bounds__(256) void k_splat(
    const float* __restrict__ feat, const int* __restrict__ cnt,
    const uint2* __restrict__ entries, float* __restrict__ out)
{
    __shared__ float plane[10000];
    __shared__ float ftab[144];           // feat[b, n, c, hw] for this c
    int bid = blockIdx.x;
    int b   = bid >> 8;
    int rem = bid & 255;
    int c   = rem >> 2;
    int q   = rem & 3;
    int t   = threadIdx.x;

    for (int i = t; i < 10000; i += 256) plane[i] = 0.f;
    if (t < 144) {
        int n  = t / HW;
        int hw = t - n * HW;
        ftab[t] = feat[(size_t)(b * N_ + n) * (C_ * HW) + c * HW + hw];
    }
    __syncthreads();

    const int ne = cnt[b * 4 + q];
    const uint2* eb = entries + (size_t)(b * 4 + q) * PPB;
    for (int i = t; i < ne; i += 256) {
        uint2 e = eb[i];
        atomicAdd(&plane[e.x & 16383u], __uint_as_float(e.y) * ftab[e.x >> 14]);
    }
    __syncthreads();

    const int lo = q * 10000;
    float4* ob = (float4*)(out + ((size_t)(b * C_ + c) * 40000) + lo);
    const float4* pl4 = (const float4*)plane;
    for (int i = t; i < 2500; i += 256) ob[i] = pl4[i];
}

// ---------------------------------------------------------------------------
extern "C" void kernel_launch(void* const* d_in, const int* in_sizes, int n_in,
                              void* d_out, int out_size, void* d_ws, size_t ws_size,
                              hipStream_t stream) {
    const float *x = nullptr, *m1 = nullptr, *m2 = nullptr, *trn = nullptr,
                *w = nullptr, *bias = nullptr;
    for (int i = 0; i < n_in; i++) {
        const float* p = (const float*)d_in[i];
        switch (in_sizes[i]) {
            case 3538944: x = p; break;
            case 1728:    if (!m1) m1 = p; else m2 = p; break;
            case 576:     trn = p; break;
            case 80640:   w = p; break;
            case 105:     bias = p; break;
            default: break;
        }
    }
    if (!x)    x    = (const float*)d_in[0];
    if (!m1)   m1   = (const float*)d_in[1];
    if (!trn)  trn  = (const float*)d_in[2];
    if (!m2)   m2   = (const float*)d_in[3];
    if (!w)    w    = (const float*)d_in[4];
    if (!bias) bias = (const float*)d_in[5];

    float* feat_ws  = (float*)d_ws;                 // 192*1536 f32
    float* depth_ws = feat_ws + 192 * C_ * HW;      // NPTS f32
    int*   cnt      = (int*)(depth_ws + NPTS);      // 128 i32
    uint2* entries  = (uint2*)(cnt + 128);          // 128*PPB uint2 (~6 MB)

    float* out    = (float*)d_out;
    float* dlogit = out + FINAL_ELEMS;

    k_conv_fused<<<192,  256, 0, stream>>>(x, w, bias, feat_ws, depth_ws, dlogit, cnt);
    k_geom      <<<738,  256, 0, stream>>>(m1, trn, m2, depth_ws, cnt, entries);
    k_splat     <<<8192, 256, 0, stream>>>(feat_ws, cnt, entries, out);
}

// Round 2
// 447.717 us; speedup vs baseline: 1.7815x; 1.7815x over previous
//
#include <hip/hip_runtime.h>
#include <hip/hip_bf16.h>

#define B_    32
#define N_    6
#define D_    41
#define C_    64
#define FH_   4
#define FW_   6
#define INCH  768
#define HW    24
#define O_    105
#define PBN   984
#define PPB   5904
#define NPTS  188928
#define FINAL_ELEMS 81920000
#define NSEG  8          // planes per b (5000 voxels each)
#define SEGV  5000       // voxels per segment
#define NBKT  (B_ * NSEG)

// ws: feat f32[192*1536] | depth f32[NPTS] | cnt i32[256] | entries uint2[256*PPB]
// entries[b*8+g][slot] = { rel(13b) | nhw(8b)<<13 , depth bits }

// ---------------------------------------------------------------------------
// K1: fused conv + softmax. One block per image. x[bn] staged to LDS in two
// 36KB halves; each thread computes 3 output rows x 4 hw cols with fmaf.
// Epilogue: softmax over D in-block; depth->ws, logits->out, feat->ws.
// Also zeroes the bucket counters (block 0) for K2.
// ---------------------------------------------------------------------------
__global__ __launch_bounds__(256) void k_conv_fused(
    const float* __restrict__ x, const float* __restrict__ w,
    const float* __restrict__ bias,
    float* __restrict__ feat_ws, float* __restrict__ depth_ws,
    float* __restrict__ dlogit, int* __restrict__ cnt)
{
    __shared__ float xs[9216];      // half of x[bn]: 384 c x 24 hw (36 KB)
    __shared__ float ys[O_ * HW];   // full y image (10 KB)
    __shared__ float smax[HW], srs[HW];

    const int bn = blockIdx.x;
    const int t  = threadIdx.x;
    const int og = t / 6;           // 35 groups x 3 rows = 105
    const int q6 = t % 6;           // hw quad

    if (bn == 0) cnt[t] = 0;        // 256 counters; stream-ordered ahead of k_geom

    float a[3][4] = {{0.f,0.f,0.f,0.f},{0.f,0.f,0.f,0.f},{0.f,0.f,0.f,0.f}};
    const int o0 = og * 3;
    const float4* wr0 = (const float4*)(w + (size_t)(o0 + 0) * INCH);
    const float4* wr1 = (const float4*)(w + (size_t)(o0 + 1) * INCH);
    const float4* wr2 = (const float4*)(w + (size_t)(o0 + 2) * INCH);
    float4* xs4 = (float4*)xs;

    for (int half = 0; half < 2; ++half) {
        if (half) __syncthreads();                 // drain half-0 readers
        const float4* xg = (const float4*)(x + (size_t)bn * (INCH * HW)) + half * 2304;
        for (int i = t; i < 2304; i += 256) xs4[i] = xg[i];
        __syncthreads();

        if (t < 210) {
            const int wb = half * 96;              // float4 index into w row
            for (int c4 = 0; c4 < 96; ++c4) {
                float4 w0 = wr0[wb + c4];
                float4 w1 = wr1[wb + c4];
                float4 w2 = wr2[wb + c4];
                int cb = c4 * 4;
                float4 x0 = xs4[(cb + 0) * 6 + q6];
                float4 x1 = xs4[(cb + 1) * 6 + q6];
                float4 x2 = xs4[(cb + 2) * 6 + q6];
                float4 x3 = xs4[(cb + 3) * 6 + q6];
                a[0][0]=fmaf(w0.x,x0.x,a[0][0]); a[0][1]=fmaf(w0.x,x0.y,a[0][1]);
                a[0][2]=fmaf(w0.x,x0.z,a[0][2]); a[0][3]=fmaf(w0.x,x0.w,a[0][3]);
                a[1][0]=fmaf(w1.x,x0.x,a[1][0]); a[1][1]=fmaf(w1.x,x0.y,a[1][1]);
                a[1][2]=fmaf(w1.x,x0.z,a[1][2]); a[1][3]=fmaf(w1.x,x0.w,a[1][3]);
                a[2][0]=fmaf(w2.x,x0.x,a[2][0]); a[2][1]=fmaf(w2.x,x0.y,a[2][1]);
                a[2][2]=fmaf(w2.x,x0.z,a[2][2]); a[2][3]=fmaf(w2.x,x0.w,a[2][3]);
                a[0][0]=fmaf(w0.y,x1.x,a[0][0]); a[0][1]=fmaf(w0.y,x1.y,a[0][1]);
                a[0][2]=fmaf(w0.y,x1.z,a[0][2]); a[0][3]=fmaf(w0.y,x1.w,a[0][3]);
                a[1][0]=fmaf(w1.y,x1.x,a[1][0]); a[1][1]=fmaf(w1.y,x1.y,a[1][1]);
                a[1][2]=fmaf(w1.y,x1.z,a[1][2]); a[1][3]=fmaf(w1.y,x1.w,a[1][3]);
                a[2][0]=fmaf(w2.y,x1.x,a[2][0]); a[2][1]=fmaf(w2.y,x1.y,a[2][1]);
                a[2][2]=fmaf(w2.y,x1.z,a[2][2]); a[2][3]=fmaf(w2.y,x1.w,a[2][3]);
                a[0][0]=fmaf(w0.z,x2.x,a[0][0]); a[0][1]=fmaf(w0.z,x2.y,a[0][1]);
                a[0][2]=fmaf(w0.z,x2.z,a[0][2]); a[0][3]=fmaf(w0.z,x2.w,a[0][3]);
                a[1][0]=fmaf(w1.z,x2.x,a[1][0]); a[1][1]=fmaf(w1.z,x2.y,a[1][1]);
                a[1][2]=fmaf(w1.z,x2.z,a[1][2]); a[1][3]=fmaf(w1.z,x2.w,a[1][3]);
                a[2][0]=fmaf(w2.z,x2.x,a[2][0]); a[2][1]=fmaf(w2.z,x2.y,a[2][1]);
                a[2][2]=fmaf(w2.z,x2.z,a[2][2]); a[2][3]=fmaf(w2.z,x2.w,a[2][3]);
                a[0][0]=fmaf(w0.w,x3.x,a[0][0]); a[0][1]=fmaf(w0.w,x3.y,a[0][1]);
                a[0][2]=fmaf(w0.w,x3.z,a[0][2]); a[0][3]=fmaf(w0.w,x3.w,a[0][3]);
                a[1][0]=fmaf(w1.w,x3.x,a[1][0]); a[1][1]=fmaf(w1.w,x3.y,a[1][1]);
                a[1][2]=fmaf(w1.w,x3.z,a[1][2]); a[1][3]=fmaf(w1.w,x3.w,a[1][3]);
                a[2][0]=fmaf(w2.w,x3.x,a[2][0]); a[2][1]=fmaf(w2.w,x3.y,a[2][1]);
                a[2][2]=fmaf(w2.w,x3.z,a[2][2]); a[2][3]=fmaf(w2.w,x3.w,a[2][3]);
            }
        }
    }

    if (t < 210) {
#pragma unroll
        for (int r = 0; r < 3; r++) {
            float bo = bias[o0 + r];
#pragma unroll
            for (int j = 0; j < 4; j++)
                ys[(o0 + r) * HW + q6 * 4 + j] = a[r][j] + bo;
        }
    }
    __syncthreads();

    if (t < HW) {
        float mx = -1e30f;
        for (int d = 0; d < D_; d++) mx = fmaxf(mx, ys[d * HW + t]);
        float s = 0.f;
        for (int d = 0; d < D_; d++) s = __fadd_rn(s, expf(__fsub_rn(ys[d * HW + t], mx)));
        smax[t] = mx; srs[t] = s;
    }
    __syncthreads();

    for (int u = t; u < D_ * HW; u += 256) {
        float yv = ys[u];
        int hw = u % HW;
        depth_ws[bn * PBN + u] = __fdiv_rn(expf(__fsub_rn(yv, smax[hw])), srs[hw]);
        dlogit[(size_t)bn * PBN + u] = yv;
    }
    for (int u = t; u < C_ * HW; u += 256)
        feat_ws[(size_t)bn * (C_ * HW) + u] = ys[D_ * HW + u];
}

// ---------------------------------------------------------------------------
// K2: geometry + bucket compaction. Binning arithmetic is BIT-IDENTICAL to the
// validated frozen version. Sink: block-aggregated append. Each 256-thread
// block spans at most 2 b values -> <=16 local (b,seg) buckets in LDS; ONE
// global atomicAdd per non-empty bucket per block (~8K total, uncontended)
// instead of one per point on 2 cachelines (the 368us regression).
// ---------------------------------------------------------------------------
__global__ __launch_bounds__(256) void k_geom(
    const float* __restrict__ m1, const float* __restrict__ trans,
    const float* __restrict__ m2, const float* __restrict__ depth,
    int* __restrict__ cnt, uint2* __restrict__ entries)
{
    __shared__ int lcnt[16], lbase[16];

    const float* rots = (fabsf(m1[0]) > 50.0f) ? m2 : m1;
    const float* intr = (fabsf(m1[0]) > 50.0f) ? m1 : m2;

    int p = blockIdx.x * 256 + threadIdx.x;   // 738*256 == 188928
    const int t = threadIdx.x;
    if (t < 16) lcnt[t] = 0;
    __syncthreads();

    int b  = p / PPB;
    int pl = p % PPB;
    int n  = pl / PBN;
    int r  = pl % PBN;
    int d  = r / HW;
    int hw = r % HW;
    int h = hw / FW_, wp = hw % FW_;

    float dv = 4.0f + (float)d;
    float xi = (float)((double)wp * (199.0 / 5.0));
    float yi = (float)((double)h  * (149.0 / 3.0));
    float px = __fmul_rn(xi, dv), py = __fmul_rn(yi, dv), pz = dv;

    int bn = b * N_ + n;
    const float* K = intr + bn * 9;
    const float* R = rots + bn * 9;
    const float* T = trans + bn * 3;

    float a00 = K[0], a01 = K[1], a02 = K[2];
    float a11 = K[4], a12 = K[5];
    float a22 = K[8];

    float i00 = __fdiv_rn(1.0f, a00);
    float i11 = __fdiv_rn(1.0f, a11);
    float x0  = __fmul_rn(a01, i00);
    float i01 = __fmul_rn(-i11, x0);
    float i22 = __fdiv_rn(1.0f, a22);
    float y0  = __fmul_rn(a02, i00);
    y0 = __fadd_rn(y0, __fmul_rn(a12, i01));
    float y1  = __fmul_rn(a12, i11);
    float i02 = __fmul_rn(-i22, y0);
    float i12 = __fmul_rn(-i22, y1);
    float i10 = 0.f, i20 = 0.f, i21 = 0.f;

    float r00 = R[0], r01 = R[1], r02 = R[2];
    float r10 = R[3], r11 = R[4], r12 = R[5];
    float r20 = R[6], r21 = R[7], r22 = R[8];

#define MM(u0,u1,u2, v0,v1,v2) \
    __fmaf_rn(u2, v2, __fmaf_rn(u1, v1, __fmul_rn(u0, v0)))
    float c00 = MM(r00, r01, r02, i00, i10, i20);
    float c01 = MM(r00, r01, r02, i01, i11, i21);
    float c02 = MM(r00, r01, r02, i02, i12, i22);
    float c10 = MM(r10, r11, r12, i00, i10, i20);
    float c11 = MM(r10, r11, r12, i01, i11, i21);
    float c12 = MM(r10, r11, r12, i02, i12, i22);
    float c20 = MM(r20, r21, r22, i00, i10, i20);
    float c21 = MM(r20, r21, r22, i01, i11, i21);
    float c22 = MM(r20, r21, r22, i02, i12, i22);
#undef MM

#define DOT3(u0,v0,u1,v1,u2,v2) \
    __fadd_rn(__fadd_rn(__fmul_rn(u0,v0), __fmul_rn(u1,v1)), __fmul_rn(u2,v2))
    float gx = __fadd_rn(DOT3(c00,px, c01,py, c02,pz), T[0]);
    float gy = __fadd_rn(DOT3(c10,px, c11,py, c12,pz), T[1]);
    float gz = __fadd_rn(DOT3(c20,px, c21,py, c22,pz), T[2]);
#undef DOT3

    int ix = (int)__fmul_rn(__fadd_rn(gx, 50.0f), 2.0f);
    int iy = (int)__fmul_rn(__fadd_rn(gy, 50.0f), 2.0f);
    int iz = (int)__fdiv_rn(__fadd_rn(gz, 10.0f), 20.0f);
    bool kept = (ix >= 0) && (ix < 200) && (iy >= 0) && (iy < 200) && (iz == 0);

    const int bmin = (blockIdx.x * 256) / PPB;    // block spans b in {bmin, bmin+1}
    int lb = 0, slot = 0, rel = 0, nhw = 0;
    if (kept) {
        int vl  = ix * 200 + iy;          // 0..39999
        int g   = vl / SEGV;              // segment 0..7
        rel = vl - g * SEGV;              // 0..4999  (13 bits)
        nhw = n * HW + hw;                // 0..143   (8 bits)
        lb  = (b - bmin) * NSEG + g;      // 0..15
        slot = atomicAdd(&lcnt[lb], 1);   // LDS atomic: fast
    }
    __syncthreads();
    if (t < 16 && lcnt[t] > 0) {
        int gb = (bmin + (t >> 3)) * NSEG + (t & 7);   // valid whenever lcnt>0
        lbase[t] = atomicAdd(&cnt[gb], lcnt[t]);
    }
    __syncthreads();
    if (kept) {
        int gb = (bmin + (lb >> 3)) * NSEG + (lb & 7);
        entries[(size_t)gb * PPB + lbase[lb] + slot] =
            make_uint2((unsigned)rel | ((unsigned)nhw << 13),
                       __float_as_uint(depth[p]));
    }
}

// ---------------------------------------------------------------------------
// K3: splat -> f32 out. One block per (b,c,segment); 20KB LDS plane (8-way
// split -> 7 blocks/CU instead of 4: store pipeline stays fed); float4 LDS
// zeroing; scans only its segment's compacted list; coalesced float4 stores.
// ---------------------------------------------------------------------------
__global__ __launch_bounds__(256) void k_splat(
    const float* __restrict__ feat, const int* __restrict__ cnt,
    const uint2* __restrict__ entries, float* __restrict__ out)
{
    __shared__ float plane[SEGV];         // 20 KB
    __shared__ float ftab[144];           // feat[b, n, c, hw] for this c
    int bid = blockIdx.x;
    int b   = bid >> 9;                   // /512
    int rem = bid & 511;
    int c   = rem >> 3;
    int g   = rem & 7;
    int t   = threadIdx.x;

    float4* pl4 = (float4*)plane;
    for (int i = t; i < SEGV / 4; i += 256) pl4[i] = make_float4(0.f, 0.f, 0.f, 0.f);
    if (t < 144) {
        int n  = t / HW;
        int hw = t - n * HW;
        ftab[t] = feat[(size_t)(b * N_ + n) * (C_ * HW) + c * HW + hw];
    }
    __syncthreads();

    const int bkt = b * NSEG + g;
    const int ne = cnt[bkt];
    const uint2* eb = entries + (size_t)bkt * PPB;
    for (int i = t; i < ne; i += 256) {
        uint2 e = eb[i];
        atomicAdd(&plane[e.x & 8191u], __uint_as_float(e.y) * ftab[e.x >> 13]);
    }
    __syncthreads();

    float4* ob = (float4*)(out + ((size_t)(b * C_ + c) * 40000) + g * SEGV);
    for (int i = t; i < SEGV / 4; i += 256) ob[i] = pl4[i];
}

// ---------------------------------------------------------------------------
extern "C" void kernel_launch(void* const* d_in, const int* in_sizes, int n_in,
                              void* d_out, int out_size, void* d_ws, size_t ws_size,
                              hipStream_t stream) {
    const float *x = nullptr, *m1 = nullptr, *m2 = nullptr, *trn = nullptr,
                *w = nullptr, *bias = nullptr;
    for (int i = 0; i < n_in; i++) {
        const float* p = (const float*)d_in[i];
        switch (in_sizes[i]) {
            case 3538944: x = p; break;
            case 1728:    if (!m1) m1 = p; else m2 = p; break;
            case 576:     trn = p; break;
            case 80640:   w = p; break;
            case 105:     bias = p; break;
            default: break;
        }
    }
    if (!x)    x    = (const float*)d_in[0];
    if (!m1)   m1   = (const float*)d_in[1];
    if (!trn)  trn  = (const float*)d_in[2];
    if (!m2)   m2   = (const float*)d_in[3];
    if (!w)    w    = (const float*)d_in[4];
    if (!bias) bias = (const float*)d_in[5];

    float* feat_ws  = (float*)d_ws;                 // 192*1536 f32
    float* depth_ws = feat_ws + 192 * C_ * HW;      // NPTS f32
    int*   cnt      = (int*)(depth_ws + NPTS);      // 256 i32
    uint2* entries  = (uint2*)(cnt + 256);          // 256*PPB uint2 (~12 MB)

    float* out    = (float*)d_out;
    float* dlogit = out + FINAL_ELEMS;

    k_conv_fused<<<192,   256, 0, stream>>>(x, w, bias, feat_ws, depth_ws, dlogit, cnt);
    k_geom      <<<738,   256, 0, stream>>>(m1, trn, m2, depth_ws, cnt, entries);
    k_splat     <<<16384, 256, 0, stream>>>(feat_ws, cnt, entries, out);
}